// Round 17
// baseline (164.626 us; speedup 1.0000x reference)
//
#include <hip/hip_runtime.h>
#include <hip/hip_bf16.h>
#include <math.h>

// ---------- types ----------
typedef __bf16 bf16x8 __attribute__((ext_vector_type(8)));
typedef float  floatx4 __attribute__((ext_vector_type(4)));
typedef float  floatx16 __attribute__((ext_vector_type(16)));
typedef unsigned u32x2 __attribute__((ext_vector_type(2)));

#define MFMA(a, b, c)   __builtin_amdgcn_mfma_f32_16x16x32_bf16((a), (b), (c), 0, 0, 0)
#define MFMA32(a, b, c) __builtin_amdgcn_mfma_f32_32x32x16_bf16((a), (b), (c), 0, 0, 0)

__device__ __forceinline__ unsigned short f2bf(float f) {
  union { float f; unsigned u; } v; v.f = f;
  unsigned r = v.u + 0x7FFFu + ((v.u >> 16) & 1u);
  return (unsigned short)(r >> 16);
}
__device__ __forceinline__ float bf2f(unsigned short u) {
  union { unsigned u; float f; } v; v.u = ((unsigned)u) << 16;
  return v.f;
}
// pack two f32 -> one dword of 2 bf16 (RNE); compiler emits v_cvt_pk_bf16_f32
__device__ __forceinline__ unsigned pack2(float a, float b) {
  __bf16 x = (__bf16)a, y = (__bf16)b;
  unsigned short ux = __builtin_bit_cast(unsigned short, x);
  unsigned short uy = __builtin_bit_cast(unsigned short, y);
  return (unsigned)ux | ((unsigned)uy << 16);
}
__device__ __forceinline__ float exp2_fast(float x) {
#if __has_builtin(__builtin_amdgcn_exp2f)
  return __builtin_amdgcn_exp2f(x);
#else
  return exp2f(x);
#endif
}

// B=4, C=256, N=4096, Ci=32, SPLITS=4
// ---------- K_wconv: Wall[320][256] bf16 = [Wq;Wk;Wv] ----------
__global__ __launch_bounds__(256) void k_wconv(const float* __restrict__ Wq,
                                               const float* __restrict__ Wk,
                                               const float* __restrict__ Wv,
                                               unsigned short* __restrict__ Wall) {
  int i = blockIdx.x * 256 + threadIdx.x;
  int o = i >> 8, c = i & 255;
  float v = (o < 32) ? Wq[o * 256 + c]
          : (o < 64) ? Wk[(o - 32) * 256 + c]
                     : Wv[(o - 64) * 256 + c];
  Wall[i] = f2bf(v);
}

// ---------- K_projx v4 (round-16, verbatim): 16-n tiles, 1024 blocks ----------
// Outputs (fragment-linear for k_attn):
//   qbf[b][qblk128][kh2][hi2][q32][8ch]   (q pre-scaled by log2e, bias folded)
//   kbf[b][tile128][kh2][hi2][key32][8ch]
//   vbf[b][kb128][cb8][kk2][hi2][ch32][8key]
__global__ __launch_bounds__(256) void k_projx(const float* __restrict__ x,
                                               const unsigned short* __restrict__ Wall,
                                               const float* __restrict__ bq,
                                               const float* __restrict__ bk,
                                               const float* __restrict__ bv,
                                               unsigned short* __restrict__ qbf,
                                               unsigned short* __restrict__ kbf,
                                               unsigned short* __restrict__ vbf) {
  int b = blockIdx.x >> 8;
  int nt = blockIdx.x & 255;        // 16-n tile index
  int m0 = nt * 16;
  int tid = threadIdx.x;
  int qr = tid >> 6;                // wave id = output quarter
  int lane = tid & 63;
  int l15 = lane & 15, quad = lane >> 4;

  __shared__ alignas(16) unsigned short xs[16][264];
  __shared__ alignas(16) unsigned short Os[4][64][24];

  {
    int g = tid & 3;
    int r0 = tid >> 2;              // 0..63
    const float* xcol = x + (size_t)b * 256 * 4096 + m0 + g * 4;
#pragma unroll
    for (int pass = 0; pass < 4; ++pass) {
      int r = pass * 64 + r0;       // channel 0..255
      float4 d = *(const float4*)(xcol + (size_t)r * 4096);
      xs[g * 4 + 0][r] = f2bf(d.x);
      xs[g * 4 + 1][r] = f2bf(d.y);
      xs[g * 4 + 2][r] = f2bf(d.z);
      xs[g * 4 + 3][r] = f2bf(d.w);
    }
  }
  __syncthreads();

  floatx4 acc[5];
#pragma unroll
  for (int tt = 0; tt < 5; ++tt) acc[tt] = floatx4{0.f, 0.f, 0.f, 0.f};

#pragma unroll
  for (int ks = 0; ks < 8; ++ks) {
    bf16x8 a = *(const bf16x8*)&xs[l15][ks * 32 + quad * 8];
    {
      bf16x8 w = *(const bf16x8*)(Wall + (size_t)(qr * 16 + l15) * 256 + ks * 32 + quad * 8);
      acc[0] = MFMA(a, w, acc[0]);
    }
#pragma unroll
    for (int t = 0; t < 4; ++t) {
      int gt = 4 + qr * 4 + t;
      bf16x8 w = *(const bf16x8*)(Wall + (size_t)(gt * 16 + l15) * 256 + ks * 32 + quad * 8);
      acc[1 + t] = MFMA(a, w, acc[1 + t]);
    }
  }
  {
    int o = qr * 16 + l15;
    float bias = (o < 32) ? bq[o] : bk[o - 32];
    float scale = (o < 32) ? 1.44269504088896340736f : 1.0f;
    unsigned short* dst = (o < 32) ? qbf : kbf;
    int oc = o & 31;
    int kh = oc >> 4, h2 = (oc >> 3) & 1, c8 = oc & 7;
#pragma unroll
    for (int r = 0; r < 4; ++r) {
      int m = m0 + quad * 4 + r;
      dst[(size_t)b * 131072 + (size_t)(m >> 5) * 1024 + kh * 512 + h2 * 256 +
          (m & 31) * 8 + c8] = f2bf((acc[0][r] + bias) * scale);
    }
  }
#pragma unroll
  for (int t = 0; t < 4; ++t) {
    int lr = t * 16 + l15;                  // local channel 0..63
    int c = qr * 64 + lr;                   // global v channel
    float bias = bv[c];
#pragma unroll
    for (int r = 0; r < 4; ++r)
      Os[qr][lr][quad * 4 + r] = f2bf(acc[1 + t][r] + bias);
  }
  {
    int kb = nt >> 1, kk = nt & 1;          // this tile = one kk-half of key-block kb
#pragma unroll
    for (int i = 0; i < 2; ++i) {
      int idx = lane + 64 * i;              // 128 granules of 16B per wave
      int r = idx >> 1, g = idx & 1;        // r = local ch 0..63, g = hi half
      int c = qr * 64 + r;
      int cb = c >> 5, ch = c & 31;
      *(uint4*)(vbf + (size_t)b * 1048576 + (size_t)kb * 8192 +
                (size_t)cb * 1024 + kk * 512 + g * 256 + ch * 8) =
          *(const uint4*)&Os[qr][r][g * 8];
    }
  }
}

// ---------- softmax helper (unchanged, verified) ----------
__device__ __forceinline__ void softmax_pack(floatx16 st, float& lp, bf16x8 (&pa)[2], int hi) {
  float p[16];
#pragma unroll
  for (int r = 0; r < 16; ++r) p[r] = exp2_fast(st[r]);
  lp += (((p[0] + p[1]) + (p[2] + p[3])) + ((p[4] + p[5]) + (p[6] + p[7]))) +
        (((p[8] + p[9]) + (p[10] + p[11])) + ((p[12] + p[13]) + (p[14] + p[15])));
  unsigned d0[4], d1[4];
#pragma unroll
  for (int t = 0; t < 4; ++t) {
    d0[t] = pack2(p[4 * t + 0], p[4 * t + 1]);
    d1[t] = pack2(p[4 * t + 2], p[4 * t + 3]);
  }
#pragma unroll
  for (int ks = 0; ks < 2; ++ks) {
#if __has_builtin(__builtin_amdgcn_permlane32_swap)
    (void)hi;
    u32x2 r0 = __builtin_amdgcn_permlane32_swap(d0[2 * ks], d0[2 * ks + 1], false, false);
    u32x2 r1 = __builtin_amdgcn_permlane32_swap(d1[2 * ks], d1[2 * ks + 1], false, false);
    union { unsigned u[4]; bf16x8 v; } u;
    u.u[0] = r0[0]; u.u[1] = r1[0]; u.u[2] = r0[1]; u.u[3] = r1[1];
    pa[ks] = u.v;
#else
    unsigned s0 = hi ? d0[2 * ks] : d0[2 * ks + 1];
    unsigned s1 = hi ? d1[2 * ks] : d1[2 * ks + 1];
    unsigned o0 = (unsigned)__shfl_xor((int)s0, 32);
    unsigned o1 = (unsigned)__shfl_xor((int)s1, 32);
    union { unsigned u[4]; bf16x8 v; } u;
    u.u[0] = hi ? o0 : d0[2 * ks];
    u.u[1] = hi ? o1 : d1[2 * ks];
    u.u[2] = hi ? d0[2 * ks + 1] : o0;
    u.u[3] = hi ? d1[2 * ks + 1] : o1;
    pa[ks] = u.v;
#endif
  }
}

// ---------- K_attn v12: 32q x 128ch waves -> 3 waves/SIMD at UNCHANGED softmax dup ----
// acc = 64 AGPR (32q x 128ch), arch ~100 VGPR -> ~165 total -> 3 waves/SIMD under
// __launch_bounds__(256,3) (v9 was capped at 2 by its 256-reg footprint).
// Softmax dup stays x2 (cw-halves), ST MFMA count device-wide unchanged; only V
// L2-reads double (measured +4us in r10) vs +50% TLP.
// Block = (b, cw, qb) with 4 waves (key-splits); fused in-LDS 4-split merge writes
// out = x + gamma * sumO / suml directly (r12-verified epilogue pattern, fp32
// 128B-contiguous stores -> no r7-style WRITE amplification).
// grid = 1024 = b(4) x cw(2) x qb(128); XCD-swizzled: XCD owns one (b,cw) V-set (1MB).
__global__ __launch_bounds__(256, 3) void k_attn(const unsigned short* __restrict__ qbf,
                                                 const unsigned short* __restrict__ kbf,
                                                 const unsigned short* __restrict__ vbf,
                                                 const float* __restrict__ x,
                                                 const float* __restrict__ gma,
                                                 float* __restrict__ out) {
  // XCD swizzle: nwg=1024, 8 XCDs -> XCD x owns decoded range [x*128, x*128+128)
  int wg = (blockIdx.x & 7) * 128 + (blockIdx.x >> 3);
  const int qb = wg & 127;                  // 32-query tile
  const int g  = wg >> 7;                   // 0..7 = b(4) x cw(2)
  const int cw = g & 1;
  const int b  = g >> 1;
  const int tid = threadIdx.x;
  const int s  = tid >> 6;                  // wave id = key-split
  const int lane = tid & 63;
  const int l31 = lane & 31;
  const int hi  = lane >> 5;
  const int q0  = qb * 32;

  __shared__ float lpL[4][32];
  __shared__ float ltot[32];
  __shared__ alignas(16) unsigned short Ol[4][128][40];   // [split][ch][q, 80B rows]

  const floatx16 z16 = {0.f, 0.f, 0.f, 0.f, 0.f, 0.f, 0.f, 0.f,
                        0.f, 0.f, 0.f, 0.f, 0.f, 0.f, 0.f, 0.f};

  // Q fragments (B-operand: col = query l31, row ch = kh*16 + hi*8 + j), hoisted.
  bf16x8 qf[2];
  {
    const unsigned short* qbase =
        qbf + (size_t)b * 131072 + (size_t)qb * 1024 + hi * 256 + l31 * 8;
    qf[0] = *(const bf16x8*)(qbase);
    qf[1] = *(const bf16x8*)(qbase + 512);
  }

  floatx16 acc[4];
#pragma unroll
  for (int j = 0; j < 4; ++j) acc[j] = z16;

  float lp = 0.f;

  // K fragment base (A-operand: row = key l31, ch = kh*16 + hi*8 + j)
  const unsigned short* krow =
      kbf + (size_t)b * 131072 + (size_t)(s * 32) * 1024 + hi * 256 + l31 * 8;
  // V fragment base (B-operand: col = channel l31, key = kk*16 + hi*8 + j);
  // this wave's 128 channels = cb in {cw*4 .. cw*4+3}
  const unsigned short* vrow =
      vbf + (size_t)b * 1048576 + (size_t)(s * 32) * 8192 + (size_t)(cw * 4) * 1024 +
      hi * 256 + l31 * 8;

  bf16x8 kf0 = *(const bf16x8*)krow;
  bf16x8 kf1 = *(const bf16x8*)(krow + 512);

  for (int it = 0; it < 32; ++it) {
    // ---- V loads first (8 x 1KB contiguous): consumed at PV; ST+softmax cover latency
    bf16x8 vb[4][2];
    const unsigned short* vit = vrow + (size_t)it * 8192;
#pragma unroll
    for (int ct = 0; ct < 4; ++ct) {
      vb[ct][0] = *(const bf16x8*)(vit + ct * 1024);
      vb[ct][1] = *(const bf16x8*)(vit + ct * 1024 + 512);
    }

    // ---- S^T: mfma(K, Q) -> col = query (in-lane P rows); one 32x32 tile ----
    floatx16 st = MFMA32(kf0, qf[0], z16);
    st = MFMA32(kf1, qf[1], st);

    // ---- K prefetch for next iter (wrapped index keeps the last dead load in-region)
    const unsigned short* kn = krow + (size_t)((it + 1) & 31) * 1024;
    kf0 = *(const bf16x8*)kn;
    kf1 = *(const bf16x8*)(kn + 512);

    // ---- in-register softmax -> PV A-fragments (raw exp2, scale pre-folded) ----
    bf16x8 pa[2];
    softmax_pack(st, lp, pa, hi);

    // ---- PV: 8 MFMAs across the 4 channel-tiles ----
    __builtin_amdgcn_s_setprio(1);
#pragma unroll
    for (int ct = 0; ct < 4; ++ct) {
      acc[ct] = MFMA32(pa[0], vb[ct][0], acc[ct]);
      acc[ct] = MFMA32(pa[1], vb[ct][1], acc[ct]);
    }
    __builtin_amdgcn_s_setprio(0);
  }

  // ---- fused cross-split reduction + normalize + residual epilogue ----
  lp += __shfl_xor(lp, 32);
  if (hi == 0) lpL[s][l31] = lp;

  // acc[ct] reg r: query (r&3)+8*(r>>2)+4*hi, channel = ct*32 + l31.
#pragma unroll
  for (int ct = 0; ct < 4; ++ct) {
#pragma unroll
    for (int gi = 0; gi < 4; ++gi) {
      unsigned w0 = pack2(acc[ct][4 * gi + 0], acc[ct][4 * gi + 1]);
      unsigned w1 = pack2(acc[ct][4 * gi + 2], acc[ct][4 * gi + 3]);
      unsigned long long w = (unsigned long long)w0 | ((unsigned long long)w1 << 32);
      *(unsigned long long*)&Ol[s][ct * 32 + l31][8 * gi + 4 * hi] = w;
    }
  }
  __syncthreads();
  if (tid < 32) {
    int q = tid;
    ltot[q] = (lpL[0][q] + lpL[1][q]) + (lpL[2][q] + lpL[3][q]);
  }
  __syncthreads();

  // merge: thread t -> ch = t>>1 (0..127), qh = t&1 (16 queries each, 64B contiguous;
  // thread pairs cover 128B segments -> full-line fp32 stores).
  {
    const float gv = gma[0];
    int ch = tid >> 1;
    int qh = tid & 1;
    int qoff = qh * 16;
    float o[16];
#pragma unroll
    for (int j = 0; j < 16; ++j) o[j] = 0.f;
#pragma unroll
    for (int sp = 0; sp < 4; ++sp) {
      const uint4* p = (const uint4*)&Ol[sp][ch][qh * 16];
      uint4 a0 = p[0], a1 = p[1];
      unsigned uu[8] = {a0.x, a0.y, a0.z, a0.w, a1.x, a1.y, a1.z, a1.w};
#pragma unroll
      for (int jj = 0; jj < 8; ++jj) {
        o[2 * jj + 0] += bf2f((unsigned short)(uu[jj] & 0xffffu));
        o[2 * jj + 1] += bf2f((unsigned short)(uu[jj] >> 16));
      }
    }
    size_t rowa = ((size_t)b * 256 + cw * 128 + ch) * 4096 + q0 + qoff;
    const float* xrow = x + rowa;
    float* orow = out + rowa;
#pragma unroll
    for (int j4 = 0; j4 < 4; ++j4) {
      float4 xv = *(const float4*)(xrow + j4 * 4);
      float4 r;
      r.x = xv.x + gv * o[j4 * 4 + 0] / ltot[qoff + j4 * 4 + 0];
      r.y = xv.y + gv * o[j4 * 4 + 1] / ltot[qoff + j4 * 4 + 1];
      r.z = xv.z + gv * o[j4 * 4 + 2] / ltot[qoff + j4 * 4 + 2];
      r.w = xv.w + gv * o[j4 * 4 + 3] / ltot[qoff + j4 * 4 + 3];
      *(float4*)(orow + j4 * 4) = r;
    }
  }
}

// ---------- launch ----------
extern "C" void kernel_launch(void* const* d_in, const int* in_sizes, int n_in,
                              void* d_out, int out_size, void* d_ws, size_t ws_size,
                              hipStream_t stream) {
  const float* x   = (const float*)d_in[0];
  const float* Wq  = (const float*)d_in[1];
  const float* bq  = (const float*)d_in[2];
  const float* Wk  = (const float*)d_in[3];
  const float* bk  = (const float*)d_in[4];
  const float* Wv  = (const float*)d_in[5];
  const float* bv  = (const float*)d_in[6];
  const float* gma = (const float*)d_in[7];
  float* out = (float*)d_out;

  // layout: [qbf][kbf][vbf][Wall]
  unsigned short* qbf  = (unsigned short*)d_ws;              // [4][128][2][2][32][8]
  unsigned short* kbf  = qbf + (size_t)4 * 131072;           // [4][128][2][2][32][8]
  unsigned short* vbf  = kbf + (size_t)4 * 131072;           // [4][128][8][2][2][32][8]
  unsigned short* Wall = vbf + (size_t)4 * 1048576;          // [320][256]

  k_wconv<<<320, 256, 0, stream>>>(Wq, Wk, Wv, Wall);
  k_projx<<<1024, 256, 0, stream>>>(x, Wall, bq, bk, bv, qbf, kbf, vbf);
  k_attn<<<1024, 256, 0, stream>>>(qbf, kbf, vbf, x, gma, out);
}